// Round 2
// baseline (2742.344 us; speedup 1.0000x reference)
//
#include <hip/hip_runtime.h>
#include <hip/hip_fp16.h>

// SGConvolution: out = A @ (A @ x), A sparse COO (edge_row sorted).
// N=100000, E=1600000, D=64.
//
// R5 -> R6: attack the gather-INSTRUCTION bound.
//  - R5 issued one VMEM gather per edge (64 lanes x 2B in one 128B row):
//    1.6M vector-memory instructions per spmm, ~16cy of addr-pipe each
//    => ~40us of pure instruction-rate cost per spmm. Bytes were never
//    the limit (table is L3-resident).
//  - R6 gathers 8 edges per global_load_dwordx4: lane l = (slot q=l>>3,
//    feature-octet f=l&7) reads features 8f..8f+7 of edge 8g+q.
//    Gather instrs/wave: 64 -> 8. Per-edge VALU ~2x lower too.
//  - Edge triples still preloaded coalesced (lane i = edge start+i), then
//    redistributed per group via __shfl (ds_bpermute).
//  - Row tracking is now PER-LANE (cur_r per slot); flush is predicated
//    per-lane atomics (atomics are per-lane addressed anyway), so boundary
//    flush traffic stays ~one row per boundary. Sorted rows => ~4-5
//    flush events per 64-edge wave.
//  - prep (cast x->fp16 + zero h16b + zero out, one dispatch) and the
//    fp16 pk-atomic intermediate carried over from R5.

#define N_NODES 100000
#define N_EDGES 1600000
#define D_FEAT  64
#define EPW     64              // edges per wave; 25000 waves exactly
#define ESLOTS  8               // edges per gather instruction (dwordx4)
#define NG      (EPW / ESLOTS)  // 8 groups per wave
#define PF      4               // prefetch depth (gathers in flight)

#define N_ELEM   (N_NODES * D_FEAT)          // 6,400,000 features
#define N_CAST   (N_ELEM / 4)                // float4 cast tasks
#define N_Z16    (N_ELEM / 8)                // 16B zero tasks (h16b, 12.8 MB)
#define N_ZOUT   (N_ELEM / 4)                // 16B zero tasks (out, 25.6 MB)
#define PREP_TASKS (N_CAST + N_Z16 + N_ZOUT) // 4,000,000 -> 15625 blocks

__device__ __forceinline__ float2 h2f2(unsigned int u) {
    __half2 h = __builtin_bit_cast(__half2, u);
    return __half22float2(h);
}

// Flush this lane's 8-feature accumulator (features 8f..8f+7 of row `row`).
// Atomics are per-lane addressed, so divergent rows across lanes are fine.
template <bool HALF_OUT>
__device__ __forceinline__ void flush_lane(void* outp, int row, int f,
                                           const float4& a, const float4& b) {
    if constexpr (HALF_OUT) {
        __half2* o = (__half2*)outp + (size_t)row * (D_FEAT / 2) + 4 * f;
        unsafeAtomicAdd(o + 0, __floats2half2_rn(a.x, a.y));   // pk_add_f16
        unsafeAtomicAdd(o + 1, __floats2half2_rn(a.z, a.w));
        unsafeAtomicAdd(o + 2, __floats2half2_rn(b.x, b.y));
        unsafeAtomicAdd(o + 3, __floats2half2_rn(b.z, b.w));
    } else {
        float* o = (float*)outp + (size_t)row * D_FEAT + 8 * f;
        atomicAdd(o + 0, a.x);
        atomicAdd(o + 1, a.y);
        atomicAdd(o + 2, a.z);
        atomicAdd(o + 3, a.w);
        atomicAdd(o + 4, b.x);
        atomicAdd(o + 5, b.y);
        atomicAdd(o + 6, b.z);
        atomicAdd(o + 7, b.w);
    }
}

template <bool HALF_OUT>
__global__ __launch_bounds__(256) void sg_spmm(
    const __half* __restrict__ h,          // [N, 64] fp16 feature table
    const int*    __restrict__ erow,       // [E] sorted destination rows
    const int*    __restrict__ ecol,       // [E] source cols
    const float*  __restrict__ eval,       // [E] edge weights
    void*         __restrict__ outp)       // [N, 64] pre-zeroed fp16 or fp32
{
    const int lane  = threadIdx.x & 63;
    const int wave  = (int)((blockIdx.x * blockDim.x + threadIdx.x) >> 6);
    const int start = wave * EPW;          // grid sized exactly; no tail

    const int q = lane >> 3;               // edge slot within group (0..7)
    const int f = lane & 7;                // feature octet (features 8f..8f+7)

    // Coalesced preload of this wave's 64 edge triples (lane i = edge start+i).
    const int   r_v = erow[start + lane];
    const int   c_v = ecol[start + lane];
    const float w_v = eval[start + lane];

    uint4 gbuf[PF];                        // prefetch ring (static indices only)

    // prologue: issue first PF gathers (each covers 8 edges)
#pragma unroll
    for (int g = 0; g < PF; ++g) {
        const int c2 = __shfl(c_v, ESLOTS * g + q);
        gbuf[g] = *(const uint4*)(h + (size_t)c2 * D_FEAT + 8 * f);
    }

    int    cur_r = __shfl(r_v, q);         // row of this lane's group-0 edge
    float4 accA = make_float4(0.f, 0.f, 0.f, 0.f);
    float4 accB = make_float4(0.f, 0.f, 0.f, 0.f);

#pragma unroll
    for (int g = 0; g < NG; ++g) {
        const int   r2 = __shfl(r_v, ESLOTS * g + q);
        const float w2 = __shfl(w_v, ESLOTS * g + q);
        const bool  chg = (r2 != cur_r);
        if (chg) {                         // rare (sorted rows); execz-skipped
            flush_lane<HALF_OUT>(outp, cur_r, f, accA, accB);
            accA = make_float4(0.f, 0.f, 0.f, 0.f);
            accB = make_float4(0.f, 0.f, 0.f, 0.f);
            cur_r = r2;
        }
        const uint4  d  = gbuf[g & (PF - 1)];
        const float2 f0 = h2f2(d.x), f1 = h2f2(d.y);
        const float2 f2 = h2f2(d.z), f3 = h2f2(d.w);
        accA.x = fmaf(w2, f0.x, accA.x);
        accA.y = fmaf(w2, f0.y, accA.y);
        accA.z = fmaf(w2, f1.x, accA.z);
        accA.w = fmaf(w2, f1.y, accA.w);
        accB.x = fmaf(w2, f2.x, accB.x);
        accB.y = fmaf(w2, f2.y, accB.y);
        accB.z = fmaf(w2, f3.x, accB.z);
        accB.w = fmaf(w2, f3.y, accB.w);
        if (g + PF < NG) {                 // prefetch group g+PF into same slot
            const int c2 = __shfl(c_v, ESLOTS * (g + PF) + q);
            gbuf[g & (PF - 1)] = *(const uint4*)(h + (size_t)c2 * D_FEAT + 8 * f);
        }
    }
    flush_lane<HALF_OUT>(outp, cur_r, f, accA, accB);
}

// Fused bookkeeping: cast x -> h16a (fp16), zero h16b (spmm1 atomic target),
// zero out (spmm2 atomic target). One dispatch replaces 2 memsets + 2 casts.
__global__ __launch_bounds__(256) void prep(
    const float* __restrict__ x,
    __half*      __restrict__ h16a,
    __half*      __restrict__ h16b,
    float*       __restrict__ out)
{
    const int i = blockIdx.x * blockDim.x + threadIdx.x;
    if (i < N_CAST) {
        const float4 v = ((const float4*)x)[i];
        const __half2 a = __floats2half2_rn(v.x, v.y);
        const __half2 b = __floats2half2_rn(v.z, v.w);
        uint2 u;
        u.x = __builtin_bit_cast(unsigned int, a);
        u.y = __builtin_bit_cast(unsigned int, b);
        ((uint2*)h16a)[i] = u;                       // single 8B store
    } else if (i < N_CAST + N_Z16) {
        ((uint4*)h16b)[i - N_CAST] = make_uint4(0u, 0u, 0u, 0u);
    } else {
        ((float4*)out)[i - (N_CAST + N_Z16)] = make_float4(0.f, 0.f, 0.f, 0.f);
    }
}

extern "C" void kernel_launch(void* const* d_in, const int* in_sizes, int n_in,
                              void* d_out, int out_size, void* d_ws, size_t ws_size,
                              hipStream_t stream) {
    const float* x    = (const float*)d_in[0];
    const int*   erow = (const int*)  d_in[1];
    const int*   ecol = (const int*)  d_in[2];
    const float* eval = (const float*)d_in[3];
    float*       out  = (float*)d_out;

    // ws layout: h16a [0, 12.8M) | h16b [12.8M, 25.6M)
    __half* h16a = (__half*)d_ws;
    __half* h16b = h16a + N_ELEM;

    const int threads     = 256;
    const int prep_blocks = PREP_TASKS / threads;             // 15625 exactly
    const int spmm_blocks = (N_EDGES / EPW) * 64 / threads;   // 6250 exactly

    prep<<<prep_blocks, threads, 0, stream>>>(x, h16a, h16b, out);
    sg_spmm<true ><<<spmm_blocks, threads, 0, stream>>>(h16a, erow, ecol, eval, h16b);
    sg_spmm<false><<<spmm_blocks, threads, 0, stream>>>(h16b, erow, ecol, eval, out);
}

// Round 3
// 806.485 us; speedup vs baseline: 3.4004x; 3.4004x over previous
//
#include <hip/hip_runtime.h>
#include <hip/hip_fp16.h>

// SGConvolution: out = A @ (A @ x), A sparse COO (edge_row sorted).
// N=100000, E=1600000, D=64.
//
// R6 -> R7: keep the 8x gather-instruction reduction, FIX the flush.
//  - R6 post-mortem: WRITE_SIZE 1.8 GB, VALUBusy 0.4% -> atomic-bound.
//    Strided slot ownership (lane's edges 8 apart in the sorted list) made
//    nearly every lane flush every group: ~64M scattered dword atomics.
//  - R7: slot q (lanes 8q..8q+7) owns CONTIGUOUS edges start+8q..start+8q+7;
//    lane (q,f) holds features 8f..8f+7. Row tracking is per-slot and
//    slot-UNIFORM -> a flush is 8 lanes writing one row's contiguous 128 B
//    (line-coalesced), and contiguous sorted edges make boundaries rare
//    (~0.44 internal boundaries per slot; ~290K slot-flushes per spmm,
//    ~37 MB atomic traffic vs R6's 1.8 GB).
//  - Edge triples preloaded coalesced (lane i = edge start+i), then
//    slot-broadcast via ds_swizzle immediates (src = (lane&~7)|j).
//  - All 8 gathers (global_load_dwordx4, 8 edges each) issued upfront into
//    statically-indexed regs; compiler inserts counted vmcnt before uses.
//  - prep (cast x->fp16 + zero h16b + zero out, one dispatch) and the
//    fp16 pk-atomic intermediate carried over from R5.

#define N_NODES 100000
#define N_EDGES 1600000
#define D_FEAT  64
#define EPW     64              // edges per wave; 25000 waves exactly

#define N_ELEM   (N_NODES * D_FEAT)          // 6,400,000 features
#define N_CAST   (N_ELEM / 4)                // float4 cast tasks
#define N_Z16    (N_ELEM / 8)                // 16B zero tasks (h16b, 12.8 MB)
#define N_ZOUT   (N_ELEM / 4)                // 16B zero tasks (out, 25.6 MB)
#define PREP_TASKS (N_CAST + N_Z16 + N_ZOUT) // 4,000,000 -> 15625 blocks

__device__ __forceinline__ float2 h2f2(unsigned int u) {
    __half2 h = __builtin_bit_cast(__half2, u);
    return __half22float2(h);
}

// Slot-broadcast: every lane reads the value held by lane (lane & ~7) | J.
// ds_swizzle BitMode: offset = (xor<<10)|(or<<5)|and, src = ((lane&and)|or)^xor
// within each 32-lane half (our 8-lane slots never cross the half boundary).
// and = 0x18 keeps the slot bits, or = J selects the edge within the slot.
#define SWZ_I(x, J) __builtin_amdgcn_ds_swizzle((x), ((J) << 5) | 0x18)
#define SWZ_F(x, J) __uint_as_float((unsigned)SWZ_I((int)__float_as_uint(x), J))

// Flush one slot's accumulator: 8 lanes (f = 0..7) write one row's 64
// features as contiguous 128 B (fp16 pk atomics) / 256 B (fp32 atomics).
template <bool HALF_OUT>
__device__ __forceinline__ void flush_slot(void* outp, int row, int f,
                                           float4& a, float4& b) {
    if constexpr (HALF_OUT) {
        __half2* o = (__half2*)outp + (size_t)row * (D_FEAT / 2) + 4 * f;
        unsafeAtomicAdd(o + 0, __floats2half2_rn(a.x, a.y));   // pk_add_f16
        unsafeAtomicAdd(o + 1, __floats2half2_rn(a.z, a.w));
        unsafeAtomicAdd(o + 2, __floats2half2_rn(b.x, b.y));
        unsafeAtomicAdd(o + 3, __floats2half2_rn(b.z, b.w));
    } else {
        float* o = (float*)outp + (size_t)row * D_FEAT + 8 * f;
        atomicAdd(o + 0, a.x); atomicAdd(o + 1, a.y);
        atomicAdd(o + 2, a.z); atomicAdd(o + 3, a.w);
        atomicAdd(o + 4, b.x); atomicAdd(o + 5, b.y);
        atomicAdd(o + 6, b.z); atomicAdd(o + 7, b.w);
    }
    a = make_float4(0.f, 0.f, 0.f, 0.f);
    b = make_float4(0.f, 0.f, 0.f, 0.f);
}

template <bool HALF_OUT>
__global__ __launch_bounds__(256) void sg_spmm(
    const __half* __restrict__ h,          // [N, 64] fp16 feature table
    const int*    __restrict__ erow,       // [E] sorted destination rows
    const int*    __restrict__ ecol,       // [E] source cols
    const float*  __restrict__ eval,       // [E] edge weights
    void*         __restrict__ outp)       // [N, 64] pre-zeroed fp16 or fp32
{
    const int lane  = threadIdx.x & 63;
    const int wave  = (int)((blockIdx.x * blockDim.x + threadIdx.x) >> 6);
    const int start = wave * EPW;          // grid sized exactly; no tail
    const int f     = lane & 7;            // feature octet (features 8f..8f+7)

    // Coalesced preload of this wave's 64 edge triples (lane i = edge start+i).
    // Slot q = lane>>3 owns edges start+8q .. start+8q+7 (contiguous).
    const int   r_v = erow[start + lane];
    const int   c_v = ecol[start + lane];
    const float w_v = eval[start + lane];

    const __half* hf = h + 8 * f;          // this lane's feature-octet base

    // Issue all 8 gathers upfront (each = 8 edges x 16 B = 1 KiB/instr).
    uint4 g0, g1, g2, g3, g4, g5, g6, g7;
#define GATHER(J, G) { const int c2 = SWZ_I(c_v, J); \
                       G = *(const uint4*)(hf + (size_t)c2 * D_FEAT); }
    GATHER(0, g0) GATHER(1, g1) GATHER(2, g2) GATHER(3, g3)
    GATHER(4, g4) GATHER(5, g5) GATHER(6, g6) GATHER(7, g7)
#undef GATHER

    int    cur_r = SWZ_I(r_v, 0);          // slot-uniform current row
    float4 accA = make_float4(0.f, 0.f, 0.f, 0.f);
    float4 accB = make_float4(0.f, 0.f, 0.f, 0.f);

#define STEP(J, G) { \
    const int   r2 = SWZ_I(r_v, J); \
    const float w2 = SWZ_F(w_v, J); \
    if (r2 != cur_r) {                     /* slot-uniform, rare */ \
        flush_slot<HALF_OUT>(outp, cur_r, f, accA, accB); \
        cur_r = r2; \
    } \
    const float2 f0 = h2f2(G.x), f1 = h2f2(G.y); \
    const float2 f2 = h2f2(G.z), f3 = h2f2(G.w); \
    accA.x = fmaf(w2, f0.x, accA.x); accA.y = fmaf(w2, f0.y, accA.y); \
    accA.z = fmaf(w2, f1.x, accA.z); accA.w = fmaf(w2, f1.y, accA.w); \
    accB.x = fmaf(w2, f2.x, accB.x); accB.y = fmaf(w2, f2.y, accB.y); \
    accB.z = fmaf(w2, f3.x, accB.z); accB.w = fmaf(w2, f3.y, accB.w); }

    STEP(0, g0) STEP(1, g1) STEP(2, g2) STEP(3, g3)
    STEP(4, g4) STEP(5, g5) STEP(6, g6) STEP(7, g7)
#undef STEP

    flush_slot<HALF_OUT>(outp, cur_r, f, accA, accB);
}

// Fused bookkeeping: cast x -> h16a (fp16), zero h16b (spmm1 atomic target),
// zero out (spmm2 atomic target). One dispatch replaces 2 memsets + 2 casts.
__global__ __launch_bounds__(256) void prep(
    const float* __restrict__ x,
    __half*      __restrict__ h16a,
    __half*      __restrict__ h16b,
    float*       __restrict__ out)
{
    const int i = blockIdx.x * blockDim.x + threadIdx.x;
    if (i < N_CAST) {
        const float4 v = ((const float4*)x)[i];
        const __half2 a = __floats2half2_rn(v.x, v.y);
        const __half2 b = __floats2half2_rn(v.z, v.w);
        uint2 u;
        u.x = __builtin_bit_cast(unsigned int, a);
        u.y = __builtin_bit_cast(unsigned int, b);
        ((uint2*)h16a)[i] = u;                       // single 8B store
    } else if (i < N_CAST + N_Z16) {
        ((uint4*)h16b)[i - N_CAST] = make_uint4(0u, 0u, 0u, 0u);
    } else {
        ((float4*)out)[i - (N_CAST + N_Z16)] = make_float4(0.f, 0.f, 0.f, 0.f);
    }
}

extern "C" void kernel_launch(void* const* d_in, const int* in_sizes, int n_in,
                              void* d_out, int out_size, void* d_ws, size_t ws_size,
                              hipStream_t stream) {
    const float* x    = (const float*)d_in[0];
    const int*   erow = (const int*)  d_in[1];
    const int*   ecol = (const int*)  d_in[2];
    const float* eval = (const float*)d_in[3];
    float*       out  = (float*)d_out;

    // ws layout: h16a [0, 12.8M) | h16b [12.8M, 25.6M)
    __half* h16a = (__half*)d_ws;
    __half* h16b = h16a + N_ELEM;

    const int threads     = 256;
    const int prep_blocks = PREP_TASKS / threads;             // 15625 exactly
    const int spmm_blocks = (N_EDGES / EPW) * 64 / threads;   // 6250 exactly

    prep<<<prep_blocks, threads, 0, stream>>>(x, h16a, h16b, out);
    sg_spmm<true ><<<spmm_blocks, threads, 0, stream>>>(h16a, erow, ecol, eval, h16b);
    sg_spmm<false><<<spmm_blocks, threads, 0, stream>>>(h16b, erow, ecol, eval, out);
}

// Round 5
// 154.690 us; speedup vs baseline: 17.7280x; 5.2135x over previous
//
#include <hip/hip_runtime.h>
#include <hip/hip_fp16.h>

// SGConvolution: out = A @ (A @ x), A sparse COO (edge_row sorted).
// N=100000, E=1600000, D=64 (== wave width; lane d owns feature d).
//
// R8 RERUN (previous round failed on container acquisition, not the kernel).
// R7 -> R8: REVERT to the proven R5 structure (153.9 us), + EPW 64 -> 32.
//  - R6/R7 post-mortem: TCC merges atomic lane-ops into line-RMWs only when
//    the instruction's active lanes form a DENSE CONTIGUOUS byte range.
//    R7's slot-divergent, 16B-strided flushes got zero merging: 64 B of HBM
//    writeback per 4-B atomic (WRITE_SIZE 589 MB vs ~26 MB logical).
//    Also: wide gathers hit the same 128 cache-line requests per wave as
//    narrow ones (8 scattered segments each) -> no gather win. R5's
//    wave-uniform row + scalar branch + dense flush is the right structure.
//  - EPW=32: halves the per-wave serial chain (dependent readlane/branch/
//    fmac steps) and doubles TLP (50000 waves). Metadata preload uses
//    lane&31 (lanes 32-63 duplicate edge triples; readlane j<32 unaffected).
//    Gather/flush still index features by full `lane` -> semantics identical,
//    no double counting. Flush count +~25K (still dense-merged, trivial).
//  - fp16 pk-atomic intermediate + fused prep carried over from R5.

#define N_NODES 100000
#define N_EDGES 1600000
#define D_FEAT  64
#define EPW     32    // edges per wave; 1600000 / 32 = 50000 waves exactly
#define CH      16    // gather chunk (pipeline stage) size

#define N_ELEM   (N_NODES * D_FEAT)          // 6,400,000 features
#define N_CAST   (N_ELEM / 4)                // float4 cast tasks
#define N_Z16    (N_ELEM / 8)                // 16B zero tasks (h16b, 12.8 MB)
#define N_ZOUT   (N_ELEM / 4)                // 16B zero tasks (out, 25.6 MB)
#define PREP_TASKS (N_CAST + N_Z16 + N_ZOUT) // 4,000,000 -> 15625 blocks

__device__ __forceinline__ float readlane_f(float x, int j) {
    return __uint_as_float(__builtin_amdgcn_readlane(__float_as_uint(x), j));
}

// Flush one wave-segment accumulator (64 lanes, lane d = feature d) to the
// output row. HALF_OUT: pack lane pairs into __half2 and use the native
// packed-fp16 atomic (global_atomic_pk_add_f16); else plain fp32 atomicAdd.
// Both variants: active lanes cover a dense contiguous byte range -> TCC
// merges into line-RMWs (this is what keeps WRITE_SIZE sane).
template <bool HALF_OUT>
__device__ __forceinline__ void flush(void* outp, int row, int lane, float acc) {
    if constexpr (HALF_OUT) {
        const float partner = __shfl_xor(acc, 1);      // wave-uniform call site
        if ((lane & 1) == 0) {
            __half2* o = (__half2*)outp;
            unsafeAtomicAdd(&o[(size_t)row * (D_FEAT / 2) + (lane >> 1)],
                            __floats2half2_rn(acc, partner));
        }
    } else {
        atomicAdd(&((float*)outp)[(size_t)row * D_FEAT + lane], acc);
    }
}

template <bool HALF_OUT>
__global__ __launch_bounds__(256) void sg_spmm(
    const __half* __restrict__ h,          // [N, 64] fp16 feature table
    const int*    __restrict__ erow,       // [E] sorted destination rows
    const int*    __restrict__ ecol,       // [E] source cols
    const float*  __restrict__ eval,       // [E] edge weights
    void*         __restrict__ outp)       // [N, 64] pre-zeroed fp16 or fp32
{
    const int lane  = threadIdx.x & 63;
    const int wave  = (int)((blockIdx.x * blockDim.x + threadIdx.x) >> 6);
    const int start = wave * EPW;          // grid sized exactly; no tail

    // Coalesced preload of this wave's 32 edge triples (lane i%32 = edge
    // start+i%32; upper half duplicates -- readlane j<32 reads lanes 0-31).
    const int   r_v = erow[start + (lane & (EPW - 1))];
    const int   c_v = ecol[start + (lane & (EPW - 1))];
    const float w_v = eval[start + (lane & (EPW - 1))];

    __half gbuf[2][CH];

    // prefetch chunk 0 (feature index = full lane: 64 lanes cover the row)
#pragma unroll
    for (int j = 0; j < CH; ++j) {
        const int c = __builtin_amdgcn_readlane(c_v, j);          // SGPR col
        gbuf[0][j] = h[(size_t)c * D_FEAT + lane];
    }

    int   cur_row = __builtin_amdgcn_readlane(r_v, 0);
    float acc     = 0.0f;

#pragma unroll
    for (int k = 0; k < EPW / CH; ++k) {
        if (k + 1 < EPW / CH) {
            // prefetch chunk k+1 while folding chunk k
#pragma unroll
            for (int j = 0; j < CH; ++j) {
                const int c = __builtin_amdgcn_readlane(c_v, (k + 1) * CH + j);
                gbuf[(k + 1) & 1][j] = h[(size_t)c * D_FEAT + lane];
            }
        }
#pragma unroll
        for (int j = 0; j < CH; ++j) {
            const int e = k * CH + j;
            const int r = __builtin_amdgcn_readlane(r_v, e);      // SGPR row
            if (r != cur_row) {                                   // scalar branch
                flush<HALF_OUT>(outp, cur_row, lane, acc);
                acc = 0.0f;
                cur_row = r;
            }
            acc += readlane_f(w_v, e) * __half2float(gbuf[k & 1][j]);
        }
    }
    flush<HALF_OUT>(outp, cur_row, lane, acc);
}

// Fused bookkeeping: cast x -> h16a (fp16), zero h16b (spmm1 atomic target),
// zero out (spmm2 atomic target). One dispatch replaces 2 memsets + 2 casts.
__global__ __launch_bounds__(256) void prep(
    const float* __restrict__ x,
    __half*      __restrict__ h16a,
    __half*      __restrict__ h16b,
    float*       __restrict__ out)
{
    const int i = blockIdx.x * blockDim.x + threadIdx.x;
    if (i < N_CAST) {
        const float4 v = ((const float4*)x)[i];
        const __half2 a = __floats2half2_rn(v.x, v.y);
        const __half2 b = __floats2half2_rn(v.z, v.w);
        uint2 u;
        u.x = __builtin_bit_cast(unsigned int, a);
        u.y = __builtin_bit_cast(unsigned int, b);
        ((uint2*)h16a)[i] = u;                       // single 8B store
    } else if (i < N_CAST + N_Z16) {
        ((uint4*)h16b)[i - N_CAST] = make_uint4(0u, 0u, 0u, 0u);
    } else {
        ((float4*)out)[i - (N_CAST + N_Z16)] = make_float4(0.f, 0.f, 0.f, 0.f);
    }
}

extern "C" void kernel_launch(void* const* d_in, const int* in_sizes, int n_in,
                              void* d_out, int out_size, void* d_ws, size_t ws_size,
                              hipStream_t stream) {
    const float* x    = (const float*)d_in[0];
    const int*   erow = (const int*)  d_in[1];
    const int*   ecol = (const int*)  d_in[2];
    const float* eval = (const float*)d_in[3];
    float*       out  = (float*)d_out;

    // ws layout: h16a [0, 12.8M) | h16b [12.8M, 25.6M)
    __half* h16a = (__half*)d_ws;
    __half* h16b = h16a + N_ELEM;

    const int threads     = 256;
    const int prep_blocks = PREP_TASKS / threads;             // 15625 exactly
    const int spmm_blocks = (N_EDGES / EPW) * 64 / threads;   // 12500 exactly

    prep<<<prep_blocks, threads, 0, stream>>>(x, h16a, h16b, out);
    sg_spmm<true ><<<spmm_blocks, threads, 0, stream>>>(h16a, erow, ecol, eval, h16b);
    sg_spmm<false><<<spmm_blocks, threads, 0, stream>>>(h16b, erow, ecol, eval, out);
}